// Round 4
// baseline (1184.813 us; speedup 1.0000x reference)
//
#include <hip/hip_runtime.h>
#include <float.h>

// EdgeConv (fp32):
//   out[b,o,n] = P[b,n,o] + max_{j<20} Q[b, idx[b,n,j], o]
//   P = (W1-W2)^T x + b ; Q = W2^T x
//   knn: top-20 smallest of score[m] = sq[m] - 2*x_n.x_m  (m != n)
// knn restructured: wave = 16 rows x 64 lane-columns; A wave-uniform (s_load),
// B coalesced b32; scores land in top-k layout (row r, col = lane) -> no LDS,
// no barriers. m-split x2 + sorted merge. ws ~21.6 MiB.

#define BB 8
#define FF 64
#define NN 4096
#define KK 20

// ---------------- prep: sq[b][n], Q[b][n][o] ----------------
__global__ void __launch_bounds__(256) prep_kernel(
    const float* __restrict__ x, const float* __restrict__ W,
    float* __restrict__ sq, float* __restrict__ Q)
{
  __shared__ float xs[64][65];
  __shared__ float w2[64][65];
  int t = threadIdx.x;
  int b = blockIdx.x >> 6;
  int n0 = (blockIdx.x & 63) << 6;
  const float* xb = x + (size_t)b * FF * NN;

  int nl = t & 63, fq = t >> 6;
  #pragma unroll
  for (int i = 0; i < 16; ++i) {
    int f = fq + i * 4;
    xs[f][nl] = xb[(size_t)f * NN + n0 + nl];
  }
  #pragma unroll
  for (int i = 0; i < 16; ++i) {
    int id = i * 256 + t;            // 0..4095
    int o = id >> 6, f = id & 63;
    w2[o][f] = W[o * 128 + 64 + f];  // W2
  }
  __syncthreads();

  if (t < 64) {
    float s = 0.f;
    #pragma unroll
    for (int f = 0; f < FF; ++f) { float v = xs[f][t]; s += v * v; }
    sq[b * NN + n0 + t] = s;
  }
  int o = t & 63, g = t >> 6;
  for (int i = 0; i < 16; ++i) {
    int r = g + i * 4;
    float acc = 0.f;
    #pragma unroll
    for (int f = 0; f < FF; ++f) acc += w2[o][f] * xs[f][r];
    Q[((size_t)b * NN + n0 + r) * FF + o] = acc;
  }
}

// ---------------- knn: fused scores + streaming top-20, half-scan ----------------
__global__ void __launch_bounds__(256, 4) knn_kernel(
    const float* __restrict__ x, const float* __restrict__ sq,
    float* __restrict__ vals2, int* __restrict__ ids2)
{
  const int lane = threadIdx.x & 63;
  const int g = blockIdx.x * 4 + (threadIdx.x >> 6);  // global wave id
  const int tile = g & 255;
  const int half = (g >> 8) & 1;
  const int b = g >> 9;
  const int n0 = tile * 16;

  const float* __restrict__ xb  = x  + (size_t)b * FF * NN;
  const float* __restrict__ sqb = sq + (size_t)b * NN;

  float vals[16]; int ids[16]; float kth[16];

  for (int mt = 0; mt < 32; ++mt) {
    const int m0 = half * 2048 + mt * 64;
    // acc[r] = dot(x[:, n0+r], x[:, m0+lane]); A wave-uniform -> scalar loads
    float acc[16];
    #pragma unroll
    for (int r = 0; r < 16; ++r) acc[r] = 0.f;
    const float* Ap = xb + n0;          // A[f*NN + r] (uniform)
    const float* Bp = xb + m0 + lane;   // B[f*NN]     (coalesced)
    #pragma unroll 8
    for (int f = 0; f < 64; ++f) {
      float bf = Bp[f * NN];
      #pragma unroll
      for (int r = 0; r < 16; ++r)
        acc[r] = __builtin_fmaf(Ap[f * NN + r], bf, acc[r]);
    }
    float sqv = sqb[m0 + lane];

    if (mt == 0) {
      // init: bitonic-sort the 64 candidates (value, id) ascending, take 0..19
      #pragma unroll
      for (int r = 0; r < 16; ++r) {
        float v = __builtin_fmaf(-2.f, acc[r], sqv);
        int idv = m0 + lane;
        if (idv == n0 + r) v = FLT_MAX;        // self-exclusion
        for (int k = 2; k <= 64; k <<= 1) {
          for (int j = k >> 1; j > 0; j >>= 1) {
            float pv = __shfl_xor(v, j);
            int   pi = __shfl_xor(idv, j);
            bool keepmin = (((lane & j) == 0) == ((lane & k) == 0));
            bool pl = (pv < v) || (pv == v && pi < idv);   // partner < me
            bool ml = (v < pv) || (v == pv && idv < pi);   // me < partner
            bool take = keepmin ? pl : ml;
            if (take) { v = pv; idv = pi; }
          }
        }
        vals[r] = v; ids[r] = idv;
        kth[r] = __shfl(v, 19);
      }
    } else {
      #pragma unroll
      for (int r = 0; r < 16; ++r) {
        float cand = __builtin_fmaf(-2.f, acc[r], sqv);
        if (m0 + lane == n0 + r) cand = FLT_MAX;   // self-exclusion
        unsigned long long mask = __ballot(cand < kth[r]);
        if (mask) {
          do {
            int s = __ffsll(mask) - 1;
            mask &= mask - 1;
            float cv = __shfl(cand, s);            // wave-uniform candidate
            int ci = m0 + s;
            float pv = __shfl_up(vals[r], 1);
            int   pi = __shfl_up(ids[r], 1);
            bool shift = (lane > 0) && (pv > cv);
            if (lane < KK && vals[r] > cv) {       // cv >= kth -> no-op (harmless)
              vals[r] = shift ? pv : cv;
              ids[r]  = shift ? pi : ci;
            }
          } while (mask);
          kth[r] = __shfl(vals[r], 19);
        }
      }
    }
  }

  if (lane < KK) {
    #pragma unroll
    for (int r = 0; r < 16; ++r) {
      size_t rowg = ((size_t)b * NN + n0 + r) * 2 + half;
      vals2[rowg * KK + lane] = vals[r];
      ids2 [rowg * KK + lane] = ids[r];
    }
  }
}

// ---------------- merge two sorted 20-lists per row ----------------
__global__ void __launch_bounds__(256) merge_kernel(
    const float* __restrict__ vals2, const int* __restrict__ ids2,
    int* __restrict__ idxOut)
{
  int row = blockIdx.x * 256 + threadIdx.x;   // 0..32767
  if (row >= BB * NN) return;
  const float* va = vals2 + (size_t)row * 2 * KK;
  const float* vb = va + KK;
  const int* ia = ids2 + (size_t)row * 2 * KK;
  const int* ib = ia + KK;
  int a = 0, c = 0;
  int* op = idxOut + (size_t)row * KK;
  #pragma unroll
  for (int q = 0; q < KK; ++q) {
    float x1 = va[a], x2 = vb[c];
    bool ta = !(x2 < x1);          // tie -> half0 (smaller ids, stable)
    op[q] = ta ? ia[a] : ib[c];
    a += ta; c += !ta;
  }
}

// ---------------- gather: out[b,o,n] = P + max_j Q[nbr_j] ----------------
__global__ void __launch_bounds__(256) gather_kernel(
    const float* __restrict__ x, const float* __restrict__ W,
    const float* __restrict__ bias,
    const float* __restrict__ Q, const int* __restrict__ idxIn,
    float* __restrict__ out)
{
  __shared__ float xs[64][65];
  __shared__ float wp[64][65];
  __shared__ float ot[64][65];
  __shared__ float bs[64];
  int t = threadIdx.x;
  int b = blockIdx.x >> 6;
  int n0 = (blockIdx.x & 63) << 6;
  const float* xb = x + (size_t)b * FF * NN;

  int nl0 = t & 63, fq = t >> 6;
  #pragma unroll
  for (int i = 0; i < 16; ++i) {
    int f = fq + i * 4;
    xs[f][nl0] = xb[(size_t)f * NN + n0 + nl0];
  }
  #pragma unroll
  for (int i = 0; i < 16; ++i) {
    int id = i * 256 + t;            // 0..4095
    int o = id >> 6, f = id & 63;
    wp[o][f] = W[o * 128 + f] - W[o * 128 + 64 + f];   // W1 - W2
  }
  if (t < 64) bs[t] = bias[t];
  __syncthreads();

  int o = t & 63, g = t >> 6;
  for (int i = 0; i < 16; ++i) {
    int nl = g + i * 4;
    int n = n0 + nl;
    float p = bs[o];
    #pragma unroll
    for (int f = 0; f < FF; ++f) p += wp[o][f] * xs[f][nl];
    const int* ip = idxIn + ((size_t)b * NN + n) * KK;
    float m = -FLT_MAX;
    #pragma unroll
    for (int j = 0; j < KK; ++j) {
      int nb = ip[j];                                   // wave-uniform
      m = fmaxf(m, Q[((size_t)b * NN + nb) * FF + o]);  // 256B coalesced
    }
    ot[nl][o] = p + m;
  }
  __syncthreads();
  for (int i = 0; i < 16; ++i) {
    int o2 = g + i * 4;
    int nl = t & 63;
    out[((size_t)b * FF + o2) * NN + n0 + nl] = ot[nl][o2];
  }
}

extern "C" void kernel_launch(void* const* d_in, const int* in_sizes, int n_in,
                              void* d_out, int out_size, void* d_ws, size_t ws_size,
                              hipStream_t stream)
{
  const float* x    = (const float*)d_in[0];
  const float* W    = (const float*)d_in[1];
  const float* bias = (const float*)d_in[2];
  float* out = (float*)d_out;

  int*   idxb  = (int*)d_ws;                              // 8*4096*20
  float* sq    = (float*)(idxb + (size_t)BB * NN * KK);   // 8*4096
  float* Q     = sq + (size_t)BB * NN;                    // 8*4096*64
  float* vals2 = Q + (size_t)BB * NN * FF;                // 8*4096*2*20
  int*   ids2  = (int*)(vals2 + (size_t)BB * NN * 2 * KK);// 8*4096*2*20

  prep_kernel<<<BB * (NN / 64), 256, 0, stream>>>(x, W, sq, Q);
  knn_kernel<<<BB * NN / 16 * 2 / 4, 256, 0, stream>>>(x, sq, vals2, ids2);  // 1024 blocks
  merge_kernel<<<(BB * NN + 255) / 256, 256, 0, stream>>>(vals2, ids2, idxb);
  gather_kernel<<<BB * (NN / 64), 256, 0, stream>>>(x, W, bias, Q, idxb, out);
}

// Round 5
// 914.280 us; speedup vs baseline: 1.2959x; 1.2959x over previous
//
#include <hip/hip_runtime.h>
#include <hip/hip_bf16.h>
#include <float.h>

// EdgeConv (fp32 I/O):
//   out[b,o,n] = P[b,n,o] + max_{j<20} Q[b, idx[b,n,j], o]
//   P = (W1-W2)^T x + b ; Q = W2^T x
//   knn: top-20 smallest of score[m] = sq[m] - 2*x_n.x_m  (m != n)
// Round 5: score GEMM via bf16x3-split MFMA (fp32-accurate), scores emerge in
// C-layout where each 32-lane half holds 16 rows x 32 cand-columns -> ballot
// insertion with no LDS/barriers. m-split x2 + sorted merge. ws ~42 MiB.

#define BB 8
#define FF 64
#define NN 4096
#define KK 20

typedef unsigned short ushort_t;
typedef __attribute__((ext_vector_type(8))) short short8;
typedef __attribute__((ext_vector_type(16))) float float16;

// ---------------- prep: sq, Q, bf16 planes ph/pm/pl in [b][n][k] ----------------
__global__ void __launch_bounds__(256) prep_kernel(
    const float* __restrict__ x, const float* __restrict__ W,
    float* __restrict__ sq, float* __restrict__ Q,
    ushort_t* __restrict__ ph, ushort_t* __restrict__ pm, ushort_t* __restrict__ pl)
{
  __shared__ float xs[64][65];
  __shared__ float w2[64][65];
  int t = threadIdx.x;
  int b = blockIdx.x >> 6;
  int n0 = (blockIdx.x & 63) << 6;
  const float* xb = x + (size_t)b * FF * NN;

  int nl = t & 63, fq = t >> 6;
  #pragma unroll
  for (int i = 0; i < 16; ++i) {
    int f = fq + i * 4;
    xs[f][nl] = xb[(size_t)f * NN + n0 + nl];
  }
  #pragma unroll
  for (int i = 0; i < 16; ++i) {
    int id = i * 256 + t;            // 0..4095
    int o = id >> 6, f = id & 63;
    w2[o][f] = W[o * 128 + 64 + f];  // W2
  }
  __syncthreads();

  if (t < 64) {
    float s = 0.f;
    #pragma unroll
    for (int f = 0; f < FF; ++f) { float v = xs[f][t]; s += v * v; }
    sq[b * NN + n0 + t] = s;
  }
  int o = t & 63, g = t >> 6;
  for (int i = 0; i < 16; ++i) {
    int r = g + i * 4;
    float acc = 0.f;
    #pragma unroll
    for (int f = 0; f < FF; ++f) acc += w2[o][f] * xs[f][r];
    Q[((size_t)b * NN + n0 + r) * FF + o] = acc;

    // bf16x3 split of x[f=o][n=n0+r] -> planes [n][k=o]
    float v = xs[o][r];
    __hip_bfloat16 hb = __float2bfloat16(v);
    float vh = __bfloat162float(hb);
    float r1 = v - vh;                       // exact (Sterbenz)
    __hip_bfloat16 mb = __float2bfloat16(r1);
    float vm = __bfloat162float(mb);
    __hip_bfloat16 lb = __float2bfloat16(r1 - vm);
    size_t pb = ((size_t)b * NN + n0 + r) * FF + o;
    ph[pb] = __bfloat16_as_ushort(hb);
    pm[pb] = __bfloat16_as_ushort(mb);
    pl[pb] = __bfloat16_as_ushort(lb);
  }
}

// ---------------- knn: MFMA scores + in-layout streaming top-20 ----------------
__global__ void __launch_bounds__(256, 2) knn_kernel(
    const ushort_t* __restrict__ ph, const ushort_t* __restrict__ pm,
    const ushort_t* __restrict__ pl, const float* __restrict__ sq,
    float* __restrict__ vals2, int* __restrict__ ids2)
{
  const int t = threadIdx.x;
  const int lane = t & 63;
  const int l31 = lane & 31;
  const int hf = lane >> 5;
  const int wv = t >> 6;
  const int blk = blockIdx.x;
  const int b = blk >> 6;
  const int g = (blk >> 1) & 31;
  const int half = blk & 1;
  const int n0 = (g * 4 + wv) * 32;

  const float* __restrict__ sqb = sq + (size_t)b * NN;

  // A fragments (queries), resident: row = n0 + l31, k = 16*s + 8*hf + j
  short8 Ah[4], Am[4], Al[4];
  {
    size_t abase = ((size_t)b * NN + n0 + l31) * FF + hf * 8;
    #pragma unroll
    for (int s = 0; s < 4; ++s) {
      Ah[s] = *(const short8*)(ph + abase + s * 16);
      Am[s] = *(const short8*)(pm + abase + s * 16);
      Al[s] = *(const short8*)(pl + abase + s * 16);
    }
  }

  float vals[16], kth[16]; int ids[16];
  #pragma unroll
  for (int r = 0; r < 16; ++r) { vals[r] = FLT_MAX; ids[r] = 0; kth[r] = FLT_MAX; }

  for (int mc = 0; mc < 64; ++mc) {
    const int m0 = half * 2048 + mc * 32;
    size_t bbase = ((size_t)b * NN + m0 + l31) * FF + hf * 8;

    float16 acc;
    #pragma unroll
    for (int q = 0; q < 16; ++q) acc[q] = 0.f;

    short8 B0[4];
    #pragma unroll
    for (int s = 0; s < 4; ++s) B0[s] = *(const short8*)(ph + bbase + s * 16);
    #pragma unroll
    for (int s = 0; s < 4; ++s) acc = __builtin_amdgcn_mfma_f32_32x32x16_bf16(Ah[s], B0[s], acc, 0, 0, 0);
    #pragma unroll
    for (int s = 0; s < 4; ++s) acc = __builtin_amdgcn_mfma_f32_32x32x16_bf16(Am[s], B0[s], acc, 0, 0, 0);
    #pragma unroll
    for (int s = 0; s < 4; ++s) acc = __builtin_amdgcn_mfma_f32_32x32x16_bf16(Al[s], B0[s], acc, 0, 0, 0);
    #pragma unroll
    for (int s = 0; s < 4; ++s) B0[s] = *(const short8*)(pm + bbase + s * 16);
    #pragma unroll
    for (int s = 0; s < 4; ++s) acc = __builtin_amdgcn_mfma_f32_32x32x16_bf16(Ah[s], B0[s], acc, 0, 0, 0);
    #pragma unroll
    for (int s = 0; s < 4; ++s) acc = __builtin_amdgcn_mfma_f32_32x32x16_bf16(Am[s], B0[s], acc, 0, 0, 0);
    #pragma unroll
    for (int s = 0; s < 4; ++s) B0[s] = *(const short8*)(pl + bbase + s * 16);
    #pragma unroll
    for (int s = 0; s < 4; ++s) acc = __builtin_amdgcn_mfma_f32_32x32x16_bf16(Ah[s], B0[s], acc, 0, 0, 0);

    float sqv = sqb[m0 + l31];

    // top-20 update per row slot; row n = n0 + (r&3) + 8*(r>>2) + 4*hf, col m = m0 + l31
    #pragma unroll
    for (int r = 0; r < 16; ++r) {
      float cand = __builtin_fmaf(-2.f, acc[r], sqv);
      int nrow = n0 + (r & 3) + 8 * (r >> 2) + 4 * hf;
      if (m0 + l31 == nrow) cand = FLT_MAX;          // self-exclusion
      unsigned long long bal = __ballot(cand < kth[r]);
      unsigned mh = hf ? (unsigned)(bal >> 32) : (unsigned)bal;
      while (__any(mh != 0)) {
        bool act = (mh != 0);
        int s2 = act ? (__ffs(mh) - 1) : 0;
        mh &= mh - 1;
        float cv = __shfl(cand, s2, 32);
        int ci = m0 + s2;
        float pv = __shfl_up(vals[r], 1, 32);
        int pi = __shfl_up(ids[r], 1, 32);
        bool shift = (l31 > 0) && (pv > cv);
        if (act && l31 < KK && vals[r] > cv) {
          vals[r] = shift ? pv : cv;
          ids[r]  = shift ? pi : ci;
        }
      }
      kth[r] = __shfl(vals[r], 19, 32);
    }
  }

  if (l31 < KK) {
    #pragma unroll
    for (int r = 0; r < 16; ++r) {
      int nrow = n0 + (r & 3) + 8 * (r >> 2) + 4 * hf;
      size_t rowg = ((size_t)b * NN + nrow) * 2 + half;
      vals2[rowg * KK + l31] = vals[r];
      ids2 [rowg * KK + l31] = ids[r];
    }
  }
}

// ---------------- merge two sorted 20-lists per row ----------------
__global__ void __launch_bounds__(256) merge_kernel(
    const float* __restrict__ vals2, const int* __restrict__ ids2,
    int* __restrict__ idxOut)
{
  int row = blockIdx.x * 256 + threadIdx.x;   // 0..32767
  if (row >= BB * NN) return;
  const float* va = vals2 + (size_t)row * 2 * KK;
  const float* vb = va + KK;
  const int* ia = ids2 + (size_t)row * 2 * KK;
  const int* ib = ia + KK;
  int a = 0, c = 0;
  int* op = idxOut + (size_t)row * KK;
  #pragma unroll
  for (int q = 0; q < KK; ++q) {
    float x1 = va[a], x2 = vb[c];
    bool ta = !(x2 < x1);          // tie -> half0 (smaller ids, stable)
    op[q] = ta ? ia[a] : ib[c];
    a += ta; c += !ta;
  }
}

// ---------------- gather: out[b,o,n] = P + max_j Q[nbr_j] ----------------
__global__ void __launch_bounds__(256) gather_kernel(
    const float* __restrict__ x, const float* __restrict__ W,
    const float* __restrict__ bias,
    const float* __restrict__ Q, const int* __restrict__ idxIn,
    float* __restrict__ out)
{
  __shared__ float xs[64][65];
  __shared__ float wp[64][65];
  __shared__ float ot[64][65];
  __shared__ float bs[64];
  int t = threadIdx.x;
  int b = blockIdx.x >> 6;
  int n0 = (blockIdx.x & 63) << 6;
  const float* xb = x + (size_t)b * FF * NN;

  int nl0 = t & 63, fq = t >> 6;
  #pragma unroll
  for (int i = 0; i < 16; ++i) {
    int f = fq + i * 4;
    xs[f][nl0] = xb[(size_t)f * NN + n0 + nl0];
  }
  #pragma unroll
  for (int i = 0; i < 16; ++i) {
    int id = i * 256 + t;            // 0..4095
    int o = id >> 6, f = id & 63;
    wp[o][f] = W[o * 128 + f] - W[o * 128 + 64 + f];   // W1 - W2
  }
  if (t < 64) bs[t] = bias[t];
  __syncthreads();

  int o = t & 63, g = t >> 6;
  for (int i = 0; i < 16; ++i) {
    int nl = g + i * 4;
    int n = n0 + nl;
    float p = bs[o];
    #pragma unroll
    for (int f = 0; f < FF; ++f) p += wp[o][f] * xs[f][nl];
    const int* ip = idxIn + ((size_t)b * NN + n) * KK;
    float m = -FLT_MAX;
    #pragma unroll
    for (int j = 0; j < KK; ++j) {
      int nb = ip[j];                                   // wave-uniform
      m = fmaxf(m, Q[((size_t)b * NN + nb) * FF + o]);  // 256B coalesced
    }
    ot[nl][o] = p + m;
  }
  __syncthreads();
  for (int i = 0; i < 16; ++i) {
    int o2 = g + i * 4;
    int nl = t & 63;
    out[((size_t)b * FF + o2) * NN + n0 + nl] = ot[nl][o2];
  }
}

extern "C" void kernel_launch(void* const* d_in, const int* in_sizes, int n_in,
                              void* d_out, int out_size, void* d_ws, size_t ws_size,
                              hipStream_t stream)
{
  const float* x    = (const float*)d_in[0];
  const float* W    = (const float*)d_in[1];
  const float* bias = (const float*)d_in[2];
  float* out = (float*)d_out;

  int*   idxb  = (int*)d_ws;                               // 8*4096*20
  float* sq    = (float*)(idxb + (size_t)BB * NN * KK);    // 8*4096
  float* Q     = sq + (size_t)BB * NN;                     // 8*4096*64
  float* vals2 = Q + (size_t)BB * NN * FF;                 // 8*4096*2*20
  int*   ids2  = (int*)(vals2 + (size_t)BB * NN * 2 * KK); // 8*4096*2*20
  ushort_t* ph = (ushort_t*)(ids2 + (size_t)BB * NN * 2 * KK);
  ushort_t* pm = ph + (size_t)BB * NN * FF;
  ushort_t* pl = pm + (size_t)BB * NN * FF;

  prep_kernel<<<BB * (NN / 64), 256, 0, stream>>>(x, W, sq, Q, ph, pm, pl);
  knn_kernel<<<BB * 32 * 2, 256, 0, stream>>>(ph, pm, pl, sq, vals2, ids2);
  merge_kernel<<<(BB * NN + 255) / 256, 256, 0, stream>>>(vals2, ids2, idxb);
  gather_kernel<<<BB * (NN / 64), 256, 0, stream>>>(x, W, bias, Q, idxb, out);
}

// Round 6
// 526.596 us; speedup vs baseline: 2.2499x; 1.7362x over previous
//
#include <hip/hip_runtime.h>
#include <hip/hip_bf16.h>
#include <float.h>

// EdgeConv (fp32 I/O):
//   out[b,o,n] = P[b,n,o] + max_{j<20} Q[b, idx[b,n,j], o]
//   P = (W1-W2)^T x + b ; Q = W2^T x
//   knn: top-20 smallest of score[m] = sq[m] - 2*x_n.x_m  (m != n)
// Round 6 knn: two-pass threshold filter.
//   Pass A: MFMA scores, per-lane min2 per row -> tau_r = 22nd smallest of 64
//           per-lane minima (>= true k20 guaranteed).
//   Pass B: identical MFMA recompute; survivors (<= tau, ~26/row) compacted to
//           LDS as u64 keys (monotonic-val<<32 | id); one pair-bitonic sort of
//           64 keys/row -> sorted top-20. No serial insert chains.

#define BB 8
#define FF 64
#define NN 4096
#define KK 20
#define CAP 56

typedef unsigned short ushort_t;
typedef unsigned long long u64;
typedef __attribute__((ext_vector_type(8))) short short8;
typedef __attribute__((ext_vector_type(16))) float float16;

// ---------------- prep: sq, Q, bf16 planes ph/pm/pl in [b][n][k] ----------------
__global__ void __launch_bounds__(256) prep_kernel(
    const float* __restrict__ x, const float* __restrict__ W,
    float* __restrict__ sq, float* __restrict__ Q,
    ushort_t* __restrict__ ph, ushort_t* __restrict__ pm, ushort_t* __restrict__ pl)
{
  __shared__ float xs[64][65];
  __shared__ float w2[64][65];
  int t = threadIdx.x;
  int b = blockIdx.x >> 6;
  int n0 = (blockIdx.x & 63) << 6;
  const float* xb = x + (size_t)b * FF * NN;

  int nl = t & 63, fq = t >> 6;
  #pragma unroll
  for (int i = 0; i < 16; ++i) {
    int f = fq + i * 4;
    xs[f][nl] = xb[(size_t)f * NN + n0 + nl];
  }
  #pragma unroll
  for (int i = 0; i < 16; ++i) {
    int id = i * 256 + t;            // 0..4095
    int o = id >> 6, f = id & 63;
    w2[o][f] = W[o * 128 + 64 + f];  // W2
  }
  __syncthreads();

  if (t < 64) {
    float s = 0.f;
    #pragma unroll
    for (int f = 0; f < FF; ++f) { float v = xs[f][t]; s += v * v; }
    sq[b * NN + n0 + t] = s;
  }
  int o = t & 63, g = t >> 6;
  for (int i = 0; i < 16; ++i) {
    int r = g + i * 4;
    float acc = 0.f;
    #pragma unroll
    for (int f = 0; f < FF; ++f) acc += w2[o][f] * xs[f][r];
    Q[((size_t)b * NN + n0 + r) * FF + o] = acc;

    // bf16x3 split of x[f=o][n=n0+r] -> planes [n][k=o]
    float v = xs[o][r];
    __hip_bfloat16 hb = __float2bfloat16(v);
    float vh = __bfloat162float(hb);
    float r1 = v - vh;
    __hip_bfloat16 mb = __float2bfloat16(r1);
    float vm = __bfloat162float(mb);
    __hip_bfloat16 lb = __float2bfloat16(r1 - vm);
    size_t pb = ((size_t)b * NN + n0 + r) * FF + o;
    ph[pb] = __bfloat16_as_ushort(hb);
    pm[pb] = __bfloat16_as_ushort(mb);
    pl[pb] = __bfloat16_as_ushort(lb);
  }
}

// identical 24-MFMA score chunk (bitwise same in both passes)
__device__ __forceinline__ void score_chunk(
    const ushort_t* __restrict__ ph, const ushort_t* __restrict__ pm,
    const ushort_t* __restrict__ pl, size_t bbase,
    const short8* Ah, const short8* Am, const short8* Al, float16& acc)
{
  short8 B0[4];
  #pragma unroll
  for (int s = 0; s < 4; ++s) B0[s] = *(const short8*)(ph + bbase + s * 16);
  #pragma unroll
  for (int s = 0; s < 4; ++s) acc = __builtin_amdgcn_mfma_f32_32x32x16_bf16(Ah[s], B0[s], acc, 0, 0, 0);
  #pragma unroll
  for (int s = 0; s < 4; ++s) acc = __builtin_amdgcn_mfma_f32_32x32x16_bf16(Am[s], B0[s], acc, 0, 0, 0);
  #pragma unroll
  for (int s = 0; s < 4; ++s) acc = __builtin_amdgcn_mfma_f32_32x32x16_bf16(Al[s], B0[s], acc, 0, 0, 0);
  #pragma unroll
  for (int s = 0; s < 4; ++s) B0[s] = *(const short8*)(pm + bbase + s * 16);
  #pragma unroll
  for (int s = 0; s < 4; ++s) acc = __builtin_amdgcn_mfma_f32_32x32x16_bf16(Ah[s], B0[s], acc, 0, 0, 0);
  #pragma unroll
  for (int s = 0; s < 4; ++s) acc = __builtin_amdgcn_mfma_f32_32x32x16_bf16(Am[s], B0[s], acc, 0, 0, 0);
  #pragma unroll
  for (int s = 0; s < 4; ++s) B0[s] = *(const short8*)(pl + bbase + s * 16);
  #pragma unroll
  for (int s = 0; s < 4; ++s) acc = __builtin_amdgcn_mfma_f32_32x32x16_bf16(Ah[s], B0[s], acc, 0, 0, 0);
}

// ascending bitonic sort of 64 floats held as elements (2l, 2l+1) across 32 lanes
__device__ __forceinline__ void bitonic64f(float& v0, float& v1, int l31)
{
  #pragma unroll
  for (int k = 2; k <= 64; k <<= 1) {
    #pragma unroll
    for (int j = k >> 1; j >= 1; j >>= 1) {
      bool dirup = ((2 * l31) & k) == 0;
      if (j >= 2) {
        int lj = j >> 1;
        float p0 = __shfl_xor(v0, lj, 32);
        float p1 = __shfl_xor(v1, lj, 32);
        bool lower = (l31 & lj) == 0;
        bool keepmin = (dirup == lower);
        v0 = keepmin ? fminf(v0, p0) : fmaxf(v0, p0);
        v1 = keepmin ? fminf(v1, p1) : fmaxf(v1, p1);
      } else {
        float lo = fminf(v0, v1), hi = fmaxf(v0, v1);
        v0 = dirup ? lo : hi;
        v1 = dirup ? hi : lo;
      }
    }
  }
}

// same network on u64 keys
__device__ __forceinline__ void bitonic64k(u64& v0, u64& v1, int l31)
{
  #pragma unroll
  for (int k = 2; k <= 64; k <<= 1) {
    #pragma unroll
    for (int j = k >> 1; j >= 1; j >>= 1) {
      bool dirup = ((2 * l31) & k) == 0;
      if (j >= 2) {
        int lj = j >> 1;
        u64 p0 = __shfl_xor(v0, lj, 32);
        u64 p1 = __shfl_xor(v1, lj, 32);
        bool lower = (l31 & lj) == 0;
        bool keepmin = (dirup == lower);
        u64 a0 = v0 < p0 ? v0 : p0, b0 = v0 < p0 ? p0 : v0;
        u64 a1 = v1 < p1 ? v1 : p1, b1 = v1 < p1 ? p1 : v1;
        v0 = keepmin ? a0 : b0;
        v1 = keepmin ? a1 : b1;
      } else {
        u64 lo = v0 < v1 ? v0 : v1, hi = v0 < v1 ? v1 : v0;
        v0 = dirup ? lo : hi;
        v1 = dirup ? hi : lo;
      }
    }
  }
}

// ---------------- knn: two-pass threshold filter ----------------
__global__ void __launch_bounds__(256, 2) knn_kernel(
    const ushort_t* __restrict__ ph, const ushort_t* __restrict__ pm,
    const ushort_t* __restrict__ pl, const float* __restrict__ sq,
    u64* __restrict__ keys2)
{
  __shared__ u64 buf[4][32][CAP];

  const int t = threadIdx.x;
  const int lane = t & 63;
  const int l31 = lane & 31;
  const int hf = lane >> 5;
  const int wv = t >> 6;
  const int blk = blockIdx.x;
  const int b = blk >> 6;
  const int g = (blk >> 1) & 31;
  const int half = blk & 1;
  const int n0 = (g * 4 + wv) * 32;

  const float* __restrict__ sqb = sq + (size_t)b * NN;

  // resident A fragments: row = n0 + l31, k = 16*s + 8*hf + j
  short8 Ah[4], Am[4], Al[4];
  {
    size_t abase = ((size_t)b * NN + n0 + l31) * FF + hf * 8;
    #pragma unroll
    for (int s = 0; s < 4; ++s) {
      Ah[s] = *(const short8*)(ph + abase + s * 16);
      Am[s] = *(const short8*)(pm + abase + s * 16);
      Al[s] = *(const short8*)(pl + abase + s * 16);
    }
  }

  // -------- pass A: per-lane min2 per row --------
  float m1[16], m2[16];
  #pragma unroll
  for (int r = 0; r < 16; ++r) { m1[r] = FLT_MAX; m2[r] = FLT_MAX; }

  for (int mc = 0; mc < 64; ++mc) {
    const int m0 = half * 2048 + mc * 32;
    size_t bbase = ((size_t)b * NN + m0 + l31) * FF + hf * 8;
    float16 acc;
    #pragma unroll
    for (int q = 0; q < 16; ++q) acc[q] = 0.f;
    score_chunk(ph, pm, pl, bbase, Ah, Am, Al, acc);
    float sqv = sqb[m0 + l31];
    #pragma unroll
    for (int r = 0; r < 16; ++r) {
      float cand = __builtin_fmaf(-2.f, acc[r], sqv);
      int nrow = n0 + (r & 3) + 8 * (r >> 2) + 4 * hf;
      if (m0 + l31 == nrow) cand = FLT_MAX;       // self-exclusion
      m2[r] = fminf(m2[r], fmaxf(cand, m1[r]));
      m1[r] = fminf(m1[r], cand);
    }
  }

  // tau_r = 22nd smallest (0-based 21) of the 64 per-lane minima
  float tau[16];
  #pragma unroll
  for (int r = 0; r < 16; ++r) {
    float v0 = m1[r], v1 = m2[r];
    bitonic64f(v0, v1, l31);
    tau[r] = __shfl(v1, 10, 32);                  // element 21 = lane 10, reg 1
  }

  // -------- pass B: recompute, compact survivors to LDS --------
  int cnt[16];
  #pragma unroll
  for (int r = 0; r < 16; ++r) cnt[r] = 0;

  for (int mc = 0; mc < 64; ++mc) {
    const int m0 = half * 2048 + mc * 32;
    size_t bbase = ((size_t)b * NN + m0 + l31) * FF + hf * 8;
    float16 acc;
    #pragma unroll
    for (int q = 0; q < 16; ++q) acc[q] = 0.f;
    score_chunk(ph, pm, pl, bbase, Ah, Am, Al, acc);
    float sqv = sqb[m0 + l31];
    #pragma unroll
    for (int r = 0; r < 16; ++r) {
      float cand = __builtin_fmaf(-2.f, acc[r], sqv);
      int nrow = n0 + (r & 3) + 8 * (r >> 2) + 4 * hf;
      bool ok = (m0 + l31 != nrow) && (cand <= tau[r]);
      unsigned long long bal = __ballot(ok);
      unsigned mh = hf ? (unsigned)(bal >> 32) : (unsigned)bal;
      if (mh) {
        int pre = __popc(mh & ((1u << l31) - 1u));
        int slot = cnt[r] + pre;
        if (ok && slot < CAP) {
          unsigned bits = __float_as_uint(cand);
          unsigned key32 = bits ^ ((bits >> 31) ? 0xFFFFFFFFu : 0x80000000u);
          buf[wv][r + 16 * hf][slot] = ((u64)key32 << 32) | (unsigned)(m0 + l31);
        }
        cnt[r] += __popc(mh);
      }
    }
  }

  // -------- final: sort survivors per row, emit sorted top-20 keys --------
  #pragma unroll
  for (int r = 0; r < 16; ++r) {
    int c = cnt[r] < CAP ? cnt[r] : CAP;
    int rr = r + 16 * hf;
    u64 k0 = (2 * l31     < c) ? buf[wv][rr][2 * l31]     : ~0ull;
    u64 k1 = (2 * l31 + 1 < c) ? buf[wv][rr][2 * l31 + 1] : ~0ull;
    bitonic64k(k0, k1, l31);
    u64 a = __shfl(k0, l31 >> 1, 32);
    u64 b2 = __shfl(k1, l31 >> 1, 32);
    u64 kv = (l31 & 1) ? b2 : a;
    if (l31 < KK) {
      int nrow = n0 + (r & 3) + 8 * (r >> 2) + 4 * hf;
      size_t rowg = ((size_t)b * NN + nrow) * 2 + half;
      keys2[rowg * KK + l31] = kv;
    }
  }
}

// ---------------- merge two sorted 20-key lists per row ----------------
__global__ void __launch_bounds__(256) merge_kernel(
    const u64* __restrict__ keys2, int* __restrict__ idxOut)
{
  int row = blockIdx.x * 256 + threadIdx.x;   // 0..32767
  if (row >= BB * NN) return;
  const u64* ka = keys2 + (size_t)row * 2 * KK;
  const u64* kb = ka + KK;
  int a = 0, c = 0;
  int* op = idxOut + (size_t)row * KK;
  #pragma unroll
  for (int q = 0; q < KK; ++q) {
    u64 x1 = ka[a], x2 = kb[c];
    bool ta = x1 <= x2;
    op[q] = (int)(unsigned)((ta ? x1 : x2) & 0xFFFFFFFFull);
    a += ta; c += !ta;
  }
}

// ---------------- gather: out[b,o,n] = P + max_j Q[nbr_j] ----------------
__global__ void __launch_bounds__(256) gather_kernel(
    const float* __restrict__ x, const float* __restrict__ W,
    const float* __restrict__ bias,
    const float* __restrict__ Q, const int* __restrict__ idxIn,
    float* __restrict__ out)
{
  __shared__ float xs[64][65];
  __shared__ float wp[64][65];
  __shared__ float ot[64][65];
  __shared__ float bs[64];
  int t = threadIdx.x;
  int b = blockIdx.x >> 6;
  int n0 = (blockIdx.x & 63) << 6;
  const float* xb = x + (size_t)b * FF * NN;

  int nl0 = t & 63, fq = t >> 6;
  #pragma unroll
  for (int i = 0; i < 16; ++i) {
    int f = fq + i * 4;
    xs[f][nl0] = xb[(size_t)f * NN + n0 + nl0];
  }
  #pragma unroll
  for (int i = 0; i < 16; ++i) {
    int id = i * 256 + t;            // 0..4095
    int o = id >> 6, f = id & 63;
    wp[o][f] = W[o * 128 + f] - W[o * 128 + 64 + f];   // W1 - W2
  }
  if (t < 64) bs[t] = bias[t];
  __syncthreads();

  int o = t & 63, g = t >> 6;
  for (int i = 0; i < 16; ++i) {
    int nl = g + i * 4;
    int n = n0 + nl;
    float p = bs[o];
    #pragma unroll
    for (int f = 0; f < FF; ++f) p += wp[o][f] * xs[f][nl];
    const int* ip = idxIn + ((size_t)b * NN + n) * KK;
    float m = -FLT_MAX;
    #pragma unroll
    for (int j = 0; j < KK; ++j) {
      int nb = ip[j];                                   // wave-uniform
      m = fmaxf(m, Q[((size_t)b * NN + nb) * FF + o]);  // 256B coalesced
    }
    ot[nl][o] = p + m;
  }
  __syncthreads();
  for (int i = 0; i < 16; ++i) {
    int o2 = g + i * 4;
    int nl = t & 63;
    out[((size_t)b * FF + o2) * NN + n0 + nl] = ot[nl][o2];
  }
}

extern "C" void kernel_launch(void* const* d_in, const int* in_sizes, int n_in,
                              void* d_out, int out_size, void* d_ws, size_t ws_size,
                              hipStream_t stream)
{
  const float* x    = (const float*)d_in[0];
  const float* W    = (const float*)d_in[1];
  const float* bias = (const float*)d_in[2];
  float* out = (float*)d_out;

  int*   idxb  = (int*)d_ws;                               // 8*4096*20
  float* sq    = (float*)(idxb + (size_t)BB * NN * KK);    // 8*4096
  float* Q     = sq + (size_t)BB * NN;                     // 8*4096*64
  u64*   keys2 = (u64*)(Q + (size_t)BB * NN * FF);         // 8*4096*2*20
  ushort_t* ph = (ushort_t*)(keys2 + (size_t)BB * NN * 2 * KK);
  ushort_t* pm = ph + (size_t)BB * NN * FF;
  ushort_t* pl = pm + (size_t)BB * NN * FF;

  prep_kernel<<<BB * (NN / 64), 256, 0, stream>>>(x, W, sq, Q, ph, pm, pl);
  knn_kernel<<<BB * 32 * 2, 256, 0, stream>>>(ph, pm, pl, sq, keys2);
  merge_kernel<<<(BB * NN + 255) / 256, 256, 0, stream>>>(keys2, idxb);
  gather_kernel<<<BB * (NN / 64), 256, 0, stream>>>(x, W, bias, Q, idxb, out);
}

// Round 7
// 407.315 us; speedup vs baseline: 2.9088x; 1.2928x over previous
//
#include <hip/hip_runtime.h>
#include <hip/hip_bf16.h>
#include <float.h>

// EdgeConv (fp32 I/O):
//   out[b,o,n] = P[b,n,o] + max_{j<20} Q[b, idx[b,n,j], o]
//   P = (W1-W2)^T x + b ; Q = W2^T x
//   knn: top-20 smallest of score[m] = sq[m] - 2*x_n.x_m  (m != n)
// Round 7: bf16 planes stored in MFMA-fragment-native tiling
//   plane[b][c=n>>5][j=k>>3][r=n&31][e=k&7]  (shorts)
// so every A/B fragment load is 32 lanes x 16B contiguous (1KB/instr, 16 segs
// vs 32 before) -> TA per chunk halves, balanced with MFMA. Algorithm identical
// to round 6 (two-pass tau filter + LDS compaction + bitonic top-20).

#define BB 8
#define FF 64
#define NN 4096
#define KK 20
#define CAP 56

typedef unsigned short ushort_t;
typedef unsigned long long u64;
typedef __attribute__((ext_vector_type(8))) short short8;
typedef __attribute__((ext_vector_type(16))) float float16;

// plane flat index (in shorts) for point n, feature k of batch b:
//   ((b*128 + (n>>5))*8 + (k>>3))*256 ... expanded: (b*128+(n>>5))*2048 + (k>>3)*256 + (n&31)*8 + (k&7)
__device__ __forceinline__ size_t plidx(int b, int n, int k) {
  return ((size_t)b * 128 + (n >> 5)) * 2048 + (size_t)(k >> 3) * 256 + (size_t)(n & 31) * 8 + (k & 7);
}

// ---------------- prep: sq, Q, bf16 planes ph/pm/pl (fragment-tiled) ----------------
__global__ void __launch_bounds__(256) prep_kernel(
    const float* __restrict__ x, const float* __restrict__ W,
    float* __restrict__ sq, float* __restrict__ Q,
    ushort_t* __restrict__ ph, ushort_t* __restrict__ pm, ushort_t* __restrict__ pl)
{
  __shared__ float xs[64][65];
  __shared__ float w2[64][65];
  int t = threadIdx.x;
  int b = blockIdx.x >> 6;
  int n0 = (blockIdx.x & 63) << 6;
  const float* xb = x + (size_t)b * FF * NN;

  int nl = t & 63, fq = t >> 6;
  #pragma unroll
  for (int i = 0; i < 16; ++i) {
    int f = fq + i * 4;
    xs[f][nl] = xb[(size_t)f * NN + n0 + nl];
  }
  #pragma unroll
  for (int i = 0; i < 16; ++i) {
    int id = i * 256 + t;            // 0..4095
    int o = id >> 6, f = id & 63;
    w2[o][f] = W[o * 128 + 64 + f];  // W2
  }
  __syncthreads();

  if (t < 64) {
    float s = 0.f;
    #pragma unroll
    for (int f = 0; f < FF; ++f) { float v = xs[f][t]; s += v * v; }
    sq[b * NN + n0 + t] = s;
  }
  int o = t & 63, g = t >> 6;
  for (int i = 0; i < 16; ++i) {
    int r = g + i * 4;
    int n = n0 + r;
    float acc = 0.f;
    #pragma unroll
    for (int f = 0; f < FF; ++f) acc += w2[o][f] * xs[f][r];
    Q[((size_t)b * NN + n) * FF + o] = acc;

    // bf16x3 split of x[k=o][n] -> fragment-tiled planes
    float v = xs[o][r];
    __hip_bfloat16 hb = __float2bfloat16(v);
    float vh = __bfloat162float(hb);
    float r1 = v - vh;
    __hip_bfloat16 mb = __float2bfloat16(r1);
    float vm = __bfloat162float(mb);
    __hip_bfloat16 lb = __float2bfloat16(r1 - vm);
    size_t pb = plidx(b, n, o);
    ph[pb] = __bfloat16_as_ushort(hb);
    pm[pb] = __bfloat16_as_ushort(mb);
    pl[pb] = __bfloat16_as_ushort(lb);
  }
}

// identical 24-MFMA score chunk; cbase = plane short-offset of (chunk, l31, hf)
__device__ __forceinline__ void score_chunk(
    const ushort_t* __restrict__ ph, const ushort_t* __restrict__ pm,
    const ushort_t* __restrict__ pl, size_t cbase,
    const short8* Ah, const short8* Am, const short8* Al, float16& acc)
{
  short8 B0[4];
  #pragma unroll
  for (int s = 0; s < 4; ++s) B0[s] = *(const short8*)(ph + cbase + s * 512);
  #pragma unroll
  for (int s = 0; s < 4; ++s) acc = __builtin_amdgcn_mfma_f32_32x32x16_bf16(Ah[s], B0[s], acc, 0, 0, 0);
  #pragma unroll
  for (int s = 0; s < 4; ++s) acc = __builtin_amdgcn_mfma_f32_32x32x16_bf16(Am[s], B0[s], acc, 0, 0, 0);
  #pragma unroll
  for (int s = 0; s < 4; ++s) acc = __builtin_amdgcn_mfma_f32_32x32x16_bf16(Al[s], B0[s], acc, 0, 0, 0);
  #pragma unroll
  for (int s = 0; s < 4; ++s) B0[s] = *(const short8*)(pm + cbase + s * 512);
  #pragma unroll
  for (int s = 0; s < 4; ++s) acc = __builtin_amdgcn_mfma_f32_32x32x16_bf16(Ah[s], B0[s], acc, 0, 0, 0);
  #pragma unroll
  for (int s = 0; s < 4; ++s) acc = __builtin_amdgcn_mfma_f32_32x32x16_bf16(Am[s], B0[s], acc, 0, 0, 0);
  #pragma unroll
  for (int s = 0; s < 4; ++s) B0[s] = *(const short8*)(pl + cbase + s * 512);
  #pragma unroll
  for (int s = 0; s < 4; ++s) acc = __builtin_amdgcn_mfma_f32_32x32x16_bf16(Ah[s], B0[s], acc, 0, 0, 0);
}

// ascending bitonic sort of 64 floats held as elements (2l, 2l+1) across 32 lanes
__device__ __forceinline__ void bitonic64f(float& v0, float& v1, int l31)
{
  #pragma unroll
  for (int k = 2; k <= 64; k <<= 1) {
    #pragma unroll
    for (int j = k >> 1; j >= 1; j >>= 1) {
      bool dirup = ((2 * l31) & k) == 0;
      if (j >= 2) {
        int lj = j >> 1;
        float p0 = __shfl_xor(v0, lj, 32);
        float p1 = __shfl_xor(v1, lj, 32);
        bool lower = (l31 & lj) == 0;
        bool keepmin = (dirup == lower);
        v0 = keepmin ? fminf(v0, p0) : fmaxf(v0, p0);
        v1 = keepmin ? fminf(v1, p1) : fmaxf(v1, p1);
      } else {
        float lo = fminf(v0, v1), hi = fmaxf(v0, v1);
        v0 = dirup ? lo : hi;
        v1 = dirup ? hi : lo;
      }
    }
  }
}

// same network on u64 keys
__device__ __forceinline__ void bitonic64k(u64& v0, u64& v1, int l31)
{
  #pragma unroll
  for (int k = 2; k <= 64; k <<= 1) {
    #pragma unroll
    for (int j = k >> 1; j >= 1; j >>= 1) {
      bool dirup = ((2 * l31) & k) == 0;
      if (j >= 2) {
        int lj = j >> 1;
        u64 p0 = __shfl_xor(v0, lj, 32);
        u64 p1 = __shfl_xor(v1, lj, 32);
        bool lower = (l31 & lj) == 0;
        bool keepmin = (dirup == lower);
        u64 a0 = v0 < p0 ? v0 : p0, b0 = v0 < p0 ? p0 : v0;
        u64 a1 = v1 < p1 ? v1 : p1, b1 = v1 < p1 ? p1 : v1;
        v0 = keepmin ? a0 : b0;
        v1 = keepmin ? a1 : b1;
      } else {
        u64 lo = v0 < v1 ? v0 : v1, hi = v0 < v1 ? v1 : v0;
        v0 = dirup ? lo : hi;
        v1 = dirup ? hi : lo;
      }
    }
  }
}

// ---------------- knn: two-pass threshold filter ----------------
__global__ void __launch_bounds__(256, 2) knn_kernel(
    const ushort_t* __restrict__ ph, const ushort_t* __restrict__ pm,
    const ushort_t* __restrict__ pl, const float* __restrict__ sq,
    u64* __restrict__ keys2)
{
  __shared__ u64 buf[4][32][CAP];

  const int t = threadIdx.x;
  const int lane = t & 63;
  const int l31 = lane & 31;
  const int hf = lane >> 5;
  const int wv = t >> 6;
  const int blk = blockIdx.x;
  const int b = blk >> 6;
  const int g = (blk >> 1) & 31;
  const int half = blk & 1;
  const int n0 = (g * 4 + wv) * 32;

  const float* __restrict__ sqb = sq + (size_t)b * NN;

  // fragment-native short-offset for (tile base n0|m0, l31, hf); +s*512 per s
  // resident A fragments: row = n0 + l31, k = 16*s + 8*hf + e
  short8 Ah[4], Am[4], Al[4];
  {
    size_t abase = ((size_t)b * 128 + (n0 >> 5)) * 2048 + (size_t)l31 * 8 + (size_t)hf * 256;
    #pragma unroll
    for (int s = 0; s < 4; ++s) {
      Ah[s] = *(const short8*)(ph + abase + s * 512);
      Am[s] = *(const short8*)(pm + abase + s * 512);
      Al[s] = *(const short8*)(pl + abase + s * 512);
    }
  }

  // -------- pass A: per-lane min2 per row --------
  float m1[16], m2[16];
  #pragma unroll
  for (int r = 0; r < 16; ++r) { m1[r] = FLT_MAX; m2[r] = FLT_MAX; }

  for (int mc = 0; mc < 64; ++mc) {
    const int m0 = half * 2048 + mc * 32;
    size_t cbase = ((size_t)b * 128 + (m0 >> 5)) * 2048 + (size_t)l31 * 8 + (size_t)hf * 256;
    float16 acc;
    #pragma unroll
    for (int q = 0; q < 16; ++q) acc[q] = 0.f;
    score_chunk(ph, pm, pl, cbase, Ah, Am, Al, acc);
    float sqv = sqb[m0 + l31];
    #pragma unroll
    for (int r = 0; r < 16; ++r) {
      float cand = __builtin_fmaf(-2.f, acc[r], sqv);
      int nrow = n0 + (r & 3) + 8 * (r >> 2) + 4 * hf;
      if (m0 + l31 == nrow) cand = FLT_MAX;       // self-exclusion
      m2[r] = fminf(m2[r], fmaxf(cand, m1[r]));
      m1[r] = fminf(m1[r], cand);
    }
  }

  // tau_r = 22nd smallest (0-based 21) of the 64 per-lane minima
  float tau[16];
  #pragma unroll
  for (int r = 0; r < 16; ++r) {
    float v0 = m1[r], v1 = m2[r];
    bitonic64f(v0, v1, l31);
    tau[r] = __shfl(v1, 10, 32);                  // element 21 = lane 10, reg 1
  }

  // -------- pass B: recompute, compact survivors to LDS --------
  int cnt[16];
  #pragma unroll
  for (int r = 0; r < 16; ++r) cnt[r] = 0;

  for (int mc = 0; mc < 64; ++mc) {
    const int m0 = half * 2048 + mc * 32;
    size_t cbase = ((size_t)b * 128 + (m0 >> 5)) * 2048 + (size_t)l31 * 8 + (size_t)hf * 256;
    float16 acc;
    #pragma unroll
    for (int q = 0; q < 16; ++q) acc[q] = 0.f;
    score_chunk(ph, pm, pl, cbase, Ah, Am, Al, acc);
    float sqv = sqb[m0 + l31];
    #pragma unroll
    for (int r = 0; r < 16; ++r) {
      float cand = __builtin_fmaf(-2.f, acc[r], sqv);
      int nrow = n0 + (r & 3) + 8 * (r >> 2) + 4 * hf;
      bool ok = (m0 + l31 != nrow) && (cand <= tau[r]);
      unsigned long long bal = __ballot(ok);
      unsigned mh = hf ? (unsigned)(bal >> 32) : (unsigned)bal;
      if (mh) {
        int pre = __popc(mh & ((1u << l31) - 1u));
        int slot = cnt[r] + pre;
        if (ok && slot < CAP) {
          unsigned bits = __float_as_uint(cand);
          unsigned key32 = bits ^ ((bits >> 31) ? 0xFFFFFFFFu : 0x80000000u);
          buf[wv][r + 16 * hf][slot] = ((u64)key32 << 32) | (unsigned)(m0 + l31);
        }
        cnt[r] += __popc(mh);
      }
    }
  }

  // -------- final: sort survivors per row, emit sorted top-20 keys --------
  #pragma unroll
  for (int r = 0; r < 16; ++r) {
    int c = cnt[r] < CAP ? cnt[r] : CAP;
    int rr = r + 16 * hf;
    u64 k0 = (2 * l31     < c) ? buf[wv][rr][2 * l31]     : ~0ull;
    u64 k1 = (2 * l31 + 1 < c) ? buf[wv][rr][2 * l31 + 1] : ~0ull;
    bitonic64k(k0, k1, l31);
    u64 a = __shfl(k0, l31 >> 1, 32);
    u64 b2 = __shfl(k1, l31 >> 1, 32);
    u64 kv = (l31 & 1) ? b2 : a;
    if (l31 < KK) {
      int nrow = n0 + (r & 3) + 8 * (r >> 2) + 4 * hf;
      size_t rowg = ((size_t)b * NN + nrow) * 2 + half;
      keys2[rowg * KK + l31] = kv;
    }
  }
}

// ---------------- merge two sorted 20-key lists per row ----------------
__global__ void __launch_bounds__(256) merge_kernel(
    const u64* __restrict__ keys2, int* __restrict__ idxOut)
{
  int row = blockIdx.x * 256 + threadIdx.x;   // 0..32767
  if (row >= BB * NN) return;
  const u64* ka = keys2 + (size_t)row * 2 * KK;
  const u64* kb = ka + KK;
  int a = 0, c = 0;
  int* op = idxOut + (size_t)row * KK;
  #pragma unroll
  for (int q = 0; q < KK; ++q) {
    u64 x1 = ka[a], x2 = kb[c];
    bool ta = x1 <= x2;
    op[q] = (int)(unsigned)((ta ? x1 : x2) & 0xFFFFFFFFull);
    a += ta; c += !ta;
  }
}

// ---------------- gather: out[b,o,n] = P + max_j Q[nbr_j] ----------------
__global__ void __launch_bounds__(256) gather_kernel(
    const float* __restrict__ x, const float* __restrict__ W,
    const float* __restrict__ bias,
    const float* __restrict__ Q, const int* __restrict__ idxIn,
    float* __restrict__ out)
{
  __shared__ float xs[64][65];
  __shared__ float wp[64][65];
  __shared__ float ot[64][65];
  __shared__ float bs[64];
  int t = threadIdx.x;
  int b = blockIdx.x >> 6;
  int n0 = (blockIdx.x & 63) << 6;
  const float* xb = x + (size_t)b * FF * NN;

  int nl0 = t & 63, fq = t >> 6;
  #pragma unroll
  for (int i = 0; i < 16; ++i) {
    int f = fq + i * 4;
    xs[f][nl0] = xb[(size_t)f * NN + n0 + nl0];
  }
  #pragma unroll
  for (int i = 0; i < 16; ++i) {
    int id = i * 256 + t;            // 0..4095
    int o = id >> 6, f = id & 63;
    wp[o][f] = W[o * 128 + f] - W[o * 128 + 64 + f];   // W1 - W2
  }
  if (t < 64) bs[t] = bias[t];
  __syncthreads();

  int o = t & 63, g = t >> 6;
  for (int i = 0; i < 16; ++i) {
    int nl = g + i * 4;
    int n = n0 + nl;
    float p = bs[o];
    #pragma unroll
    for (int f = 0; f < FF; ++f) p += wp[o][f] * xs[f][nl];
    const int* ip = idxIn + ((size_t)b * NN + n) * KK;
    float m = -FLT_MAX;
    #pragma unroll
    for (int j = 0; j < KK; ++j) {
      int nb = ip[j];                                   // wave-uniform
      m = fmaxf(m, Q[((size_t)b * NN + nb) * FF + o]);  // 256B coalesced
    }
    ot[nl][o] = p + m;
  }
  __syncthreads();
  for (int i = 0; i < 16; ++i) {
    int o2 = g + i * 4;
    int nl = t & 63;
    out[((size_t)b * FF + o2) * NN + n0 + nl] = ot[nl][o2];
  }
}

extern "C" void kernel_launch(void* const* d_in, const int* in_sizes, int n_in,
                              void* d_out, int out_size, void* d_ws, size_t ws_size,
                              hipStream_t stream)
{
  const float* x    = (const float*)d_in[0];
  const float* W    = (const float*)d_in[1];
  const float* bias = (const float*)d_in[2];
  float* out = (float*)d_out;

  int*   idxb  = (int*)d_ws;                               // 8*4096*20
  float* sq    = (float*)(idxb + (size_t)BB * NN * KK);    // 8*4096
  float* Q     = sq + (size_t)BB * NN;                     // 8*4096*64
  u64*   keys2 = (u64*)(Q + (size_t)BB * NN * FF);         // 8*4096*2*20
  ushort_t* ph = (ushort_t*)(keys2 + (size_t)BB * NN * 2 * KK);
  ushort_t* pm = ph + (size_t)BB * NN * FF;
  ushort_t* pl = pm + (size_t)BB * NN * FF;

  prep_kernel<<<BB * (NN / 64), 256, 0, stream>>>(x, W, sq, Q, ph, pm, pl);
  knn_kernel<<<BB * 32 * 2, 256, 0, stream>>>(ph, pm, pl, sq, keys2);
  merge_kernel<<<(BB * NN + 255) / 256, 256, 0, stream>>>(keys2, idxb);
  gather_kernel<<<BB * (NN / 64), 256, 0, stream>>>(x, W, bias, Q, idxb, out);
}